// Round 3
// baseline (45.043 us; speedup 1.0000x reference)
//
#include <hip/hip_runtime.h>
#include <hip/hip_bf16.h>
#include <math.h>

#define Bsz 16
#define Nn  128
#define NFd 64
#define NDd 100
#define NHd 64

typedef __attribute__((ext_vector_type(8))) short bf16x8;
typedef __attribute__((ext_vector_type(4))) float f32x4;

__device__ __forceinline__ short f2bf(float f) {
  return (short)__builtin_bit_cast(ushort, __float2bfloat16(f));
}

// ---------------- prep kernel ----------------
// blocks [0,512):   atomh[b,j,h] = b_cf[h] + sum_f AF[b,j,f]*W_cf[f,h]   (f32 -> ws)
// blocks [512,544): pack W_df -> bf16 MFMA-B fragments, K zero-padded to 128
// blocks [544,560): pack W_fc -> bf16 MFMA-B fragments (K=64)
__global__ __launch_bounds__(256) void prep_kernel(
    const float* __restrict__ AF, const float* __restrict__ Wcf,
    const float* __restrict__ bcf, const float* __restrict__ Wdf,
    const float* __restrict__ Wfc, float* __restrict__ atomh,
    ushort* __restrict__ wdfp, ushort* __restrict__ wfcp) {
  int t = threadIdx.x;
  int blk = blockIdx.x;
  if (blk < 512) {
    int row = blk * 4 + (t >> 6);        // b*N + j
    int h = t & 63;
    const float* af = AF + (size_t)row * NFd;
    float a0 = 0.f, a1 = 0.f, a2 = 0.f, a3 = 0.f;
    #pragma unroll 4
    for (int f = 0; f < NFd; f += 4) {
      a0 += af[f + 0] * Wcf[(f + 0) * NHd + h];
      a1 += af[f + 1] * Wcf[(f + 1) * NHd + h];
      a2 += af[f + 2] * Wcf[(f + 2) * NHd + h];
      a3 += af[f + 3] * Wcf[(f + 3) * NHd + h];
    }
    atomh[(size_t)row * NHd + h] = bcf[h] + ((a0 + a1) + (a2 + a3));
  } else if (blk < 544) {
    // wdfp[(grp*64 + col)*8 + e] = bf16(Wdf[k = grp*8+e][col]), 0 if k >= 100
    int idx = (blk - 512) * 256 + t;     // [0, 8192)
    int e = idx & 7;
    int col = (idx >> 3) & 63;
    int grp = idx >> 9;
    int k = grp * 8 + e;
    float v = (k < NDd) ? Wdf[k * NHd + col] : 0.f;
    wdfp[idx] = (ushort)f2bf(v);
  } else {
    int idx = (blk - 544) * 256 + t;     // [0, 4096)
    int e = idx & 7;
    int col = (idx >> 3) & 63;
    int grp = idx >> 9;
    int k = grp * 8 + e;
    wfcp[idx] = (ushort)f2bf(Wfc[k * NFd + col]);
  }
}

// ---------------- main kernel: one block per (b,i), 4 waves ----------------
// Wave w exclusively owns j-rows [32w, 32w+32) in BOTH phases -> the gated
// LDS buffer is wave-private; only the final cross-wave reduce needs a barrier.
// A-fragments of phase 1 are loaded DIRECTLY from global DM (layout matches:
// lane p = row j, lane q = k-chunk) and converted f32->bf16 in-register.
__global__ __launch_bounds__(256, 6) void dtnn_main_kernel(
    const float* __restrict__ AF,
    const float* __restrict__ DM,
    const float* __restrict__ MASK,
    const float* __restrict__ bdf,
    const float* __restrict__ atomh,
    const ushort* __restrict__ wdfp,
    const ushort* __restrict__ wfcp,
    float* __restrict__ out) {
  __shared__ ushort gbuf[Nn * 64];     // gated, bf16, XOR-swizzled: [j][h ^ ((j&7)<<3)]
  __shared__ float masklds[Nn];
  __shared__ float red[4 * 64];

  const int t  = threadIdx.x;
  const int bi = blockIdx.x;           // b*N + i
  const int b  = bi >> 7;
  const int w  = t >> 6;               // wave 0..3 -> j rows [32w, 32w+32)
  const int p  = t & 15;               // lane&15
  const int q  = (t >> 4) & 3;         // lane>>4 (within wave)
  const int l  = t & 63;

  // mask for this wave's rows (wave-private LDS region)
  if (l < 32) masklds[w * 32 + l] = MASK[(size_t)bi * Nn + w * 32 + l];

  const float* dmblk = DM + (size_t)bi * (Nn * NDd);
  const bf16x8* wdfv = reinterpret_cast<const bf16x8*>(wdfp);

  // ---- phase 1: dist_h[j,h] = dm[j,:].W_df[:,h] + b_df[h], K=100 ----
  f32x4 acc1[2][4];
  #pragma unroll
  for (int ht = 0; ht < 4; ++ht) {
    float bv = bdf[ht * 16 + p];
    acc1[0][ht] = (f32x4){bv, bv, bv, bv};
    acc1[1][ht] = (f32x4){bv, bv, bv, bv};
  }

  #pragma unroll
  for (int ks = 0; ks < 3; ++ks) {     // k = [0,96)
    bf16x8 bfr[4];
    #pragma unroll
    for (int ht = 0; ht < 4; ++ht) bfr[ht] = wdfv[(ks * 4 + q) * 64 + ht * 16 + p];
    #pragma unroll
    for (int jt = 0; jt < 2; ++jt) {
      int j = (2 * w + jt) * 16 + p;
      const float* rowp = dmblk + j * NDd + ks * 32 + q * 8;
      float4 x = *reinterpret_cast<const float4*>(rowp);
      float4 y = *reinterpret_cast<const float4*>(rowp + 4);
      bf16x8 a;
      a[0] = f2bf(x.x); a[1] = f2bf(x.y); a[2] = f2bf(x.z); a[3] = f2bf(x.w);
      a[4] = f2bf(y.x); a[5] = f2bf(y.y); a[6] = f2bf(y.z); a[7] = f2bf(y.w);
      #pragma unroll
      for (int ht = 0; ht < 4; ++ht)
        acc1[jt][ht] = __builtin_amdgcn_mfma_f32_16x16x32_bf16(a, bfr[ht], acc1[jt][ht], 0, 0, 0);
    }
  }
  {                                    // tail k = [96,100): only q==0 carries data
    bf16x8 bfr[4];
    #pragma unroll
    for (int ht = 0; ht < 4; ++ht) bfr[ht] = wdfv[(12 + q) * 64 + ht * 16 + p];
    #pragma unroll
    for (int jt = 0; jt < 2; ++jt) {
      bf16x8 a = (bf16x8){0, 0, 0, 0, 0, 0, 0, 0};
      if (q == 0) {
        int j = (2 * w + jt) * 16 + p;
        float4 x = *reinterpret_cast<const float4*>(dmblk + j * NDd + 96);
        a[0] = f2bf(x.x); a[1] = f2bf(x.y); a[2] = f2bf(x.z); a[3] = f2bf(x.w);
      }
      #pragma unroll
      for (int ht = 0; ht < 4; ++ht)
        acc1[jt][ht] = __builtin_amdgcn_mfma_f32_16x16x32_bf16(a, bfr[ht], acc1[jt][ht], 0, 0, 0);
    }
  }

  // ---- gate: acc1[j][h] *= atomh[b,j,h]  (D layout: row j=16jt+4q+r, col h=16ht+p) ----
  #pragma unroll
  for (int jt = 0; jt < 2; ++jt) {
    int jbase = (2 * w + jt) * 16 + 4 * q;
    #pragma unroll
    for (int ht = 0; ht < 4; ++ht) {
      const float* ap = atomh + ((size_t)(b * Nn + jbase)) * NHd + ht * 16 + p;
      #pragma unroll
      for (int r = 0; r < 4; ++r) acc1[jt][ht][r] *= ap[r * NHd];
    }
  }

  // ---- write gated (bf16, swizzled) to wave-private LDS rows ----
  #pragma unroll
  for (int jt = 0; jt < 2; ++jt) {
    #pragma unroll
    for (int r = 0; r < 4; ++r) {
      int j = (2 * w + jt) * 16 + 4 * q + r;
      int sw = (j & 7) << 3;
      #pragma unroll
      for (int ht = 0; ht < 4; ++ht)
        gbuf[j * 64 + ((ht * 16 + p) ^ sw)] = (ushort)f2bf(acc1[jt][ht][r]);
    }
  }
  // wave-private LDS: in-order per-wave LDS pipeline makes the data visible;
  // just forbid compiler reordering of the reads above the writes.
  asm volatile("" ::: "memory");

  // ---- phase 2: pre[j,f] = gated[j,:].W_fc[:,f], K=64 ----
  f32x4 acc2[2][4];
  #pragma unroll
  for (int jt = 0; jt < 2; ++jt)
    #pragma unroll
    for (int ft = 0; ft < 4; ++ft) acc2[jt][ft] = (f32x4){0.f, 0.f, 0.f, 0.f};

  const bf16x8* wfcv = reinterpret_cast<const bf16x8*>(wfcp);
  #pragma unroll
  for (int ks = 0; ks < 2; ++ks) {
    bf16x8 bfr[4];
    #pragma unroll
    for (int ft = 0; ft < 4; ++ft) bfr[ft] = wfcv[(ks * 4 + q) * 64 + ft * 16 + p];
    #pragma unroll
    for (int jt = 0; jt < 2; ++jt) {
      int j = (2 * w + jt) * 16 + p;
      int h0 = ks * 32 + q * 8;
      bf16x8 a = *reinterpret_cast<const bf16x8*>(&gbuf[j * 64 + (h0 ^ ((j & 7) << 3))]);
      #pragma unroll
      for (int ft = 0; ft < 4; ++ft)
        acc2[jt][ft] = __builtin_amdgcn_mfma_f32_16x16x32_bf16(a, bfr[ft], acc2[jt][ft], 0, 0, 0);
    }
  }

  // ---- mask, tanh, reduce over this wave's 32 j ----
  float s[4] = {0.f, 0.f, 0.f, 0.f};
  #pragma unroll
  for (int jt = 0; jt < 2; ++jt) {
    #pragma unroll
    for (int r = 0; r < 4; ++r) {
      int j = (2 * w + jt) * 16 + 4 * q + r;
      float m = masklds[j];
      #pragma unroll
      for (int ft = 0; ft < 4; ++ft) s[ft] += tanhf(acc2[jt][ft][r] * m);
    }
  }
  #pragma unroll
  for (int ft = 0; ft < 4; ++ft) {
    s[ft] += __shfl_xor(s[ft], 16, 64);
    s[ft] += __shfl_xor(s[ft], 32, 64);
  }
  if (q == 0) {
    #pragma unroll
    for (int ft = 0; ft < 4; ++ft) red[w * 64 + ft * 16 + p] = s[ft];
  }
  __syncthreads();   // the only cross-wave sync
  if (t < 64) {
    float tot = red[t] + red[64 + t] + red[128 + t] + red[192 + t];
    out[(size_t)bi * NFd + t] = tot + AF[(size_t)bi * NFd + t];
  }
}

extern "C" void kernel_launch(void* const* d_in, const int* in_sizes, int n_in,
                              void* d_out, int out_size, void* d_ws, size_t ws_size,
                              hipStream_t stream) {
  const float* AF   = (const float*)d_in[0];
  const float* DM   = (const float*)d_in[1];
  const float* MASK = (const float*)d_in[2];
  const float* Wcf  = (const float*)d_in[3];
  const float* Wdf  = (const float*)d_in[4];
  const float* Wfc  = (const float*)d_in[5];
  const float* bcf  = (const float*)d_in[6];
  const float* bdf  = (const float*)d_in[7];
  float* out = (float*)d_out;

  float*  atomh = (float*)d_ws;                                   // 512 KB
  ushort* wdfp  = (ushort*)((char*)d_ws + 524288);                // 16 KB (K padded to 128)
  ushort* wfcp  = (ushort*)((char*)d_ws + 524288 + 16384);        // 8 KB

  prep_kernel<<<560, 256, 0, stream>>>(AF, Wcf, bcf, Wdf, Wfc, atomh, wdfp, wfcp);
  dtnn_main_kernel<<<Bsz * Nn, 256, 0, stream>>>(AF, DM, MASK, bdf, atomh, wdfp, wfcp, out);
}